// Round 3
// baseline (426.237 us; speedup 1.0000x reference)
//
#include <hip/hip_runtime.h>

// Problem constants (B=4, S=4096, D=1024, BASE_K=256, MAX_K=512)
#define SDIM 4096
#define DDIM 1024
#define NROWS 16384
#define KOUT 512
#define CAP 768   // candidate slots per wave. For N(0,1) rows count(x>=1.0)=650±23,
                  // so [KOUT, CAP] is a >5-sigma window; anything else -> cold fallback.

// (int)bits(1.0f). Signed compare (int)u >= K0I is EXACTLY equivalent to
// f2key(u) >= f2key(1.0f) for all 2^32 bit patterns:
//   u sign=0: key=u|0x80000000 >= 0xBF800000  <=>  u >= 0x3F800000 (= signed, top bit 0)
//   u sign=1: key=~u < 0x80000000 -> never candidate; (int)u < 0 -> never candidate.
// So the fast path needs NO f2key conversion and keeps NO key[64] resident.
#define K0I 0x3F800000

__device__ __forceinline__ unsigned kob(unsigned u) {   // float-bits -> monotonic key
    return (u & 0x80000000u) ? ~u : (u | 0x80000000u);
}
__device__ __forceinline__ float key2f(unsigned k) {
    unsigned u = (k & 0x80000000u) ? (k ^ 0x80000000u) : ~k;
    return __uint_as_float(u);
}
// popcount of mask restricted to lanes below mine
__device__ __forceinline__ unsigned lt_popc(unsigned long long m) {
    return __builtin_amdgcn_mbcnt_hi((unsigned)(m >> 32),
           __builtin_amdgcn_mbcnt_lo((unsigned)(m & 0xFFFFFFFFull), 0u));
}
// Per-wave LDS ordering: drain this wave's outstanding DS ops.
// All LDS regions are wave-private slices, so no block-wide barrier needed.
__device__ __forceinline__ void wave_lds_fence() {
    asm volatile("s_waitcnt lgkmcnt(0)" ::: "memory");
}

// One WAVE per row (4 rows per 256-thread block).
// __launch_bounds__(256, 8): target 8 waves/SIMD -> VGPR cap 64 -> 32 waves/CU
// (8 blocks x 12 KB LDS = 96 KB of 160 KB). The fast path no longer holds
// key[64], so it fits; the cold fallback streams scores from L2 instead.
__global__ __launch_bounds__(256, 8) void fused_kernel(
    const float* __restrict__ scores, const float* __restrict__ Q,
    const float* __restrict__ W, const float* __restrict__ bias,
    float* __restrict__ out_topk, float* __restrict__ out_k) {

    // 12 KB: candidate buffer per wave (raw float bits), later overlaid by the
    // selected-keys list [0..511] for the sort readback.
    __shared__ unsigned cbuf[4][CAP];

    const int tid  = threadIdx.x;
    const int lane = tid & 63;
    const int wid  = tid >> 6;
    const int row  = blockIdx.x * 4 + wid;

    // ---------------- gate ----------------
    {
        const float4* q4 = (const float4*)(Q + (size_t)row * DDIM);
        const float4* w4 = (const float4*)W;
        float g = 0.f;
#pragma unroll
        for (int i = 0; i < 4; ++i) {
            float4 a = q4[lane + 64 * i];
            float4 b = w4[lane + 64 * i];
            g += a.x * b.x + a.y * b.y + a.z * b.z + a.w * b.w;
        }
#pragma unroll
        for (int off = 32; off; off >>= 1) g += __shfl_down(g, off, 64);
        if (lane == 0) {
            float x   = g + bias[0];
            float imp = 1.0f / (1.0f + expf(-x));
            out_k[row] = (float)(int)(256.0f + 256.0f * imp);
        }
    }

    const uint4* src = (const uint4*)(scores + (size_t)row * SDIM);

    // ---- fast path: single streaming pass, count + speculative compact -----
    // Raw bits are compared with ONE signed int cmp (no f2key), ballot-ranked
    // into cbuf, then DISCARDED — nothing stays resident. Writes are bounds-
    // guarded so an off-guess cannot corrupt anything; fallback recomputes.
#define FUSE_ELEM(u) do {                                   \
        bool p = (int)(u) >= K0I;                           \
        unsigned long long m = __ballot(p);                 \
        unsigned a = cnt + lt_popc(m);                      \
        if (p && a < CAP) cbuf[wid][a] = (u);               \
        cnt += (unsigned)__popcll(m);                       \
    } while (0)

    unsigned cnt = 0;
#pragma unroll
    for (int i = 0; i < 16; ++i) {
        uint4 v = src[lane + 64 * i];
        FUSE_ELEM(v.x); FUSE_ELEM(v.y); FUSE_ELEM(v.z); FUSE_ELEM(v.w);
    }
#undef FUSE_ELEM

    unsigned T    = 0;
    unsigned mtot = 0;
    bool have = (cnt >= (unsigned)KOUT) && (cnt <= (unsigned)CAP);

    if (!have) {
        // ---- COLD fallback (never taken for N(0,1) rows): exact, streaming.
        // Re-loads scores per round (L2-resident); opaque pointer defeats CSE
        // so the compiler cannot hoist 64 values into registers.
        unsigned prefix = 0, tot = 0;
        bool trig = false;
#pragma unroll 1
        for (int b = 31; b >= 0; --b) {
            const unsigned candk = prefix | (1u << b);
            const uint4* s2 = src;
            asm volatile("" : "+v"(s2));
            unsigned c = 0;
#pragma unroll 1
            for (int i = 0; i < 16; ++i) {
                uint4 v = s2[lane + 64 * i];
                c += (unsigned)(kob(v.x) >= candk) + (unsigned)(kob(v.y) >= candk)
                   + (unsigned)(kob(v.z) >= candk) + (unsigned)(kob(v.w) >= candk);
            }
#pragma unroll
            for (int off = 32; off; off >>= 1) c += __shfl_xor(c, off, 64);
            if (c >= (unsigned)KOUT) {        // wave-uniform
                prefix = candk; tot = c;
                if (c <= (unsigned)CAP) { trig = true; break; }
            }
        }
        if (trig) {
            // streaming compact of {key >= prefix} (raw bits) into cbuf
            const uint4* s2 = src;
            asm volatile("" : "+v"(s2));
            unsigned c = 0;
#pragma unroll 1
            for (int i = 0; i < 16; ++i) {
                uint4 v = s2[lane + 64 * i];
                unsigned uu[4] = {v.x, v.y, v.z, v.w};
#pragma unroll
                for (int e = 0; e < 4; ++e) {
                    bool p = kob(uu[e]) >= prefix;
                    unsigned long long m = __ballot(p);
                    unsigned a = c + lt_popc(m);
                    if (p && a < CAP) cbuf[wid][a] = uu[e];
                    c += (unsigned)__popcll(m);
                }
            }
            cnt = tot; have = true;
        } else {
            // massive-ties endpoint: T = prefix exactly, count(key > T) < 512.
            // Streaming select of KEYS > T into cbuf[0..mtot).
            T = prefix;
            const uint4* s2 = src;
            asm volatile("" : "+v"(s2));
#pragma unroll 1
            for (int i = 0; i < 16; ++i) {
                uint4 v = s2[lane + 64 * i];
                unsigned uu[4] = {v.x, v.y, v.z, v.w};
#pragma unroll
                for (int e = 0; e < 4; ++e) {
                    unsigned k = kob(uu[e]);
                    bool p = k > T;
                    unsigned long long m = __ballot(p);
                    if (p) cbuf[wid][mtot + lt_popc(m)] = k;   // mtot <= 511
                    mtot += (unsigned)__popcll(m);
                }
            }
        }
    }

    if (have) {
        wave_lds_fence();   // order compact writes before readback

        // 12 candidates/lane as KEYS; pads 0 (never >= any candk, never > T).
        // Track masked wave min/max for the phase-B skip guards.
        unsigned ck[12];
        unsigned mn = 0xFFFFFFFFu, mx = 0u;
#pragma unroll
        for (int j = 0; j < 12; ++j) {
            unsigned idx = (unsigned)lane + 64u * (unsigned)j;
            unsigned u = cbuf[wid][idx];
            unsigned k = kob(u);
            bool val = idx < cnt;
            ck[j] = val ? k : 0u;
            unsigned km = val ? k : 0xFFFFFFFFu;
            mn = km < mn ? km : mn;
            mx = ck[j] > mx ? ck[j] : mx;
        }
#pragma unroll
        for (int off = 32; off; off >>= 1) {
            unsigned a = __shfl_xor(mn, off, 64);
            unsigned b = __shfl_xor(mx, off, 64);
            mn = a < mn ? a : mn;
            mx = b > mx ? b : mx;
        }

        // ---- exact threshold: bitwise search with mn/mx skip guards --------
        // candk <= mn  -> ALL candidates pass -> set bit, no ballot (SALU only)
        // candk >  mx  -> NONE pass           -> skip bit, no ballot
        // (identical results to the unguarded search; ~12 of 32 rounds remain)
        unsigned pfx = 0;
        if (cnt > (unsigned)KOUT) {
#pragma unroll 1
            for (int b = 31; b >= 0; --b) {
                const unsigned candk = pfx | (1u << b);
                if (candk <= mn) { pfx = candk; continue; }
                if (candk > mx) continue;
                unsigned total = 0;
#pragma unroll
                for (int j = 0; j < 12; ++j)
                    total += (unsigned)__popcll(__ballot(ck[j] >= candk));
                if (total >= (unsigned)KOUT) {
                    pfx = candk;
                    if (total == (unsigned)KOUT) break;   // wave-uniform
                }
            }
        }
        // T = min{candidate >= pfx} = exact 512th-largest key overall.
        // (cnt==512 edge: pfx stays 0, tmin -> 0 via pads, select-all below.)
        unsigned tmin = 0xFFFFFFFFu;
#pragma unroll
        for (int j = 0; j < 12; ++j) {
            unsigned t = (ck[j] >= pfx) ? ck[j] : 0xFFFFFFFFu;
            tmin = t < tmin ? t : tmin;
        }
#pragma unroll
        for (int off = 32; off; off >>= 1) {
            unsigned o = __shfl_xor(tmin, off, 64);
            tmin = o < tmin ? o : tmin;
        }
        T = tmin;

        // ---- select ck > T into cbuf[wid][0..] (overlay; ck is in regs) ----
#pragma unroll
        for (int j = 0; j < 12; ++j) {
            bool p = ck[j] > T;
            unsigned long long m = __ballot(p);
            if (p) cbuf[wid][mtot + lt_popc(m)] = ck[j];
            mtot += (unsigned)__popcll(m);   // <= 512
        }
    }

    wave_lds_fence();   // order survivor writes before readback

    // ---------------- read back 8/lane, pad ties with T ---------------------
    unsigned x[8];
#pragma unroll
    for (int r = 0; r < 8; ++r) {
        unsigned idx = 8 * (unsigned)lane + r;
        unsigned v = cbuf[wid][idx];
        x[r] = (idx < mtot) ? v : T;
    }

    // ---------------- bitonic sort 512 descending, wave-private -------------
    // element index e = 8*lane + r; elem keeps max iff ((e&kk)==0)==((e&j)==0)
#pragma unroll
    for (int kk = 2; kk <= 512; kk <<= 1) {
        // cross-lane stages: j = kk/2 .. 8  (lane xor mask = j/8)
#pragma unroll
        for (int j = kk >> 1; j >= 8; j >>= 1) {
            bool km = ((((8 * lane) & kk) == 0) == (((8 * lane) & j) == 0));
#pragma unroll
            for (int r = 0; r < 8; ++r) {
                unsigned p  = __shfl_xor(x[r], j >> 3, 64);
                unsigned mx2 = x[r] > p ? x[r] : p;
                unsigned mn2 = x[r] > p ? p : x[r];
                x[r] = km ? mx2 : mn2;
            }
        }
        // in-register stages: j = min(kk/2,4) .. 1
#pragma unroll
        for (int j = (kk >> 1) < 4 ? (kk >> 1) : 4; j >= 1; j >>= 1) {
#pragma unroll
            for (int r = 0; r < 8; ++r) {
                if ((r & j) == 0) {
                    int rp = r | j;
                    unsigned a = x[r], b = x[rp];
                    bool d = (((8 * lane + r) & kk) == 0);
                    unsigned hi = a > b ? a : b;
                    unsigned lo = a > b ? b : a;
                    x[r]  = d ? hi : lo;
                    x[rp] = d ? lo : hi;
                }
            }
        }
    }

    // ---------------- store: 8 consecutive floats per lane ------------------
    float4* dst = (float4*)(out_topk + (size_t)row * KOUT);
    dst[2 * lane + 0] = make_float4(key2f(x[0]), key2f(x[1]), key2f(x[2]), key2f(x[3]));
    dst[2 * lane + 1] = make_float4(key2f(x[4]), key2f(x[5]), key2f(x[6]), key2f(x[7]));
}

extern "C" void kernel_launch(void* const* d_in, const int* in_sizes, int n_in,
                              void* d_out, int out_size, void* d_ws, size_t ws_size,
                              hipStream_t stream) {
    const float* Q      = (const float*)d_in[0];
    const float* scores = (const float*)d_in[1];
    const float* W      = (const float*)d_in[2];
    const float* b      = (const float*)d_in[3];
    float* out_topk = (float*)d_out;                        // [16384, 512]
    float* out_k    = (float*)d_out + (size_t)NROWS * KOUT; // [16384]

    fused_kernel<<<NROWS / 4, 256, 0, stream>>>(scores, Q, W, b, out_topk, out_k);
}